// Round 1
// baseline (182.738 us; speedup 1.0000x reference)
//
#include <hip/hip_runtime.h>

// ImportancePooling: N=100000 nodes, K=32 neighbors, D=64 features.
// One wave (64 lanes) per node; lane d owns feature d.
// Lanes 0..31 hold weights/neighbor ids; __shfl broadcasts per-k.

#define K_NBR 32
#define D_FEAT 64

__global__ __launch_bounds__(256) void ImportancePooling_28424093564958_kernel(
    const float* __restrict__ x,        // [N, 64]
    const int* __restrict__ neighbors,  // [N, 32]
    const float* __restrict__ weights,  // [N, 32]
    float* __restrict__ out,            // [N, 64]
    int N) {
  const int wave_id = (blockIdx.x * blockDim.x + threadIdx.x) >> 6;
  const int lane = threadIdx.x & 63;
  if (wave_id >= N) return;

  // Lanes 0..31 load this node's weights and neighbor indices.
  float w = 0.0f;
  int nb = 0;
  if (lane < K_NBR) {
    w = weights[(long)wave_id * K_NBR + lane];
    nb = neighbors[(long)wave_id * K_NBR + lane];
  }

  // Wave-wide sum (upper 32 lanes contribute 0) -> wsum in every lane.
  float wsum = w;
  #pragma unroll
  for (int off = 32; off >= 1; off >>= 1) {
    wsum += __shfl_xor(wsum, off, 64);
  }
  const float inv = (wsum > 0.0f) ? (1.0f / wsum) : 1.0f;

  // Gather-accumulate: broadcast (w_k, idx_k) from lane k; each lane reads
  // one float of the neighbor's feature row (fully coalesced 256B/row).
  float acc = 0.0f;
  #pragma unroll
  for (int k = 0; k < K_NBR; ++k) {
    const float wk = __shfl(w, k, 64);
    const int idx = __shfl(nb, k, 64);
    acc += wk * x[(long)idx * D_FEAT + lane];
  }

  out[(long)wave_id * D_FEAT + lane] = acc * inv;
}

extern "C" void kernel_launch(void* const* d_in, const int* in_sizes, int n_in,
                              void* d_out, int out_size, void* d_ws, size_t ws_size,
                              hipStream_t stream) {
  const float* x = (const float*)d_in[0];
  const int* neighbors = (const int*)d_in[1];
  const float* weights = (const float*)d_in[2];
  float* out = (float*)d_out;

  const int N = in_sizes[0] / D_FEAT;  // 100000
  const int waves_needed = N;          // one wave per node
  const int block = 256;               // 4 waves/block
  const int grid = (waves_needed * 64 + block - 1) / block;

  ImportancePooling_28424093564958_kernel<<<grid, block, 0, stream>>>(
      x, neighbors, weights, out, N);
}